// Round 4
// baseline (294.069 us; speedup 1.0000x reference)
//
#include <hip/hip_runtime.h>

#define BATCH 8
#define HH 256
#define WW 256
#define CI 64
#define CO 64
#define STYLE_IN 512

typedef __bf16 bf16x8 __attribute__((ext_vector_type(8)));
typedef float  f32x4  __attribute__((ext_vector_type(4)));
typedef unsigned short u16x8 __attribute__((ext_vector_type(8)));

// round-to-nearest-even fp32 -> bf16
static __device__ inline unsigned short f2bf(float f) {
    union { float f; unsigned int u; } a; a.f = f;
    unsigned int u = a.u;
    u += 0x7fffu + ((u >> 16) & 1u);
    return (unsigned short)(u >> 16);
}

static __device__ inline bf16x8 as_bf(u16x8 v) {
    union { u16x8 u; bf16x8 b; } c; c.u = v; return c.b;
}

// LDS-only barrier: ds ops complete (per-wave lgkmcnt) then s_barrier.
// Does NOT drain vmcnt -> global loads/stores stay in flight (T4).
static __device__ inline void lds_barrier() {
    __builtin_amdgcn_sched_barrier(0);
    asm volatile("s_waitcnt lgkmcnt(0)" ::: "memory");
    __builtin_amdgcn_sched_barrier(0);
    __builtin_amdgcn_s_barrier();
    __builtin_amdgcn_sched_barrier(0);
}

// ---------------------------------------------------------------------------
// Kernel 1: EqualLinear modulation + demodulation -> bf16 weights
// Output layout: wbf[b][tap][co][ci], tap = kh*3+kw, ci contiguous.
// Grid (BATCH, 8); blockIdx.y = co octet.
// ---------------------------------------------------------------------------
__global__ __launch_bounds__(256) void modulate_kernel(
    const float* __restrict__ style, const float* __restrict__ mod_weight,
    const float* __restrict__ mod_bias, const float* __restrict__ weight,
    unsigned short* __restrict__ wbf)
{
    const int b   = blockIdx.x;
    const int oct = blockIdx.y;          // co in [oct*8, oct*8+8)
    const int t   = threadIdx.x;
    __shared__ float sp[4][64];
    __shared__ float s_mod[64];
    __shared__ float dpart[8][32];
    __shared__ float demod[8];

    const float LIN_SCALE  = 0.044194173824159216f;  // 1/sqrt(512)
    const float CONV_SCALE = 0.041666666666666664f;  // 1/sqrt(64*9)

    {
        const int ci = t & 63, part = t >> 6;   // 4 partials per ci
        float acc = 0.f;
        const float* st = style + b * STYLE_IN + part * 128;
        const float* mw = mod_weight + part * 128 * 64 + ci;
        #pragma unroll 8
        for (int j = 0; j < 128; ++j) acc += st[j] * mw[j * 64];
        sp[part][ci] = acc;
    }
    __syncthreads();
    if (t < 64)
        s_mod[t] = (sp[0][t] + sp[1][t] + sp[2][t] + sp[3][t]) * LIN_SCALE + mod_bias[t];
    __syncthreads();

    {
        // demod partials: 8 co x 32 partials, each partial = 2 ci x 9 taps
        const int col = t >> 5, part = t & 31;
        float acc = 0.f;
        const float* wp = weight + (oct * 8 + col) * 576 + part * 18;
        #pragma unroll
        for (int ci2 = 0; ci2 < 2; ++ci2) {
            float s = s_mod[part * 2 + ci2];
            #pragma unroll
            for (int tp = 0; tp < 9; ++tp) {
                float v = wp[ci2 * 9 + tp] * s;
                acc += v * v;
            }
        }
        dpart[col][part] = acc * (CONV_SCALE * CONV_SCALE);
    }
    __syncthreads();
    if (t < 8) {
        float s = 0.f;
        #pragma unroll
        for (int p = 0; p < 32; ++p) s += dpart[t][p];
        demod[t] = rsqrtf(s + 1e-8f);
    }
    __syncthreads();

    // write 8 co x 9 taps x 64 ci = 4608 elems; ci contiguous -> coalesced
    for (int i = t; i < 4608; i += 256) {
        int ci  = i & 63;
        int col = (i >> 6) & 7;
        int tap = i >> 9;
        float v = CONV_SCALE * weight[(oct * 8 + col) * 576 + ci * 9 + tap]
                * s_mod[ci] * demod[col];
        wbf[((b * 9 + tap) * 64 + oct * 8 + col) * 64 + ci] = f2bf(v);
    }
}

// ---------------------------------------------------------------------------
// Kernel 2: implicit-GEMM conv. OCCUPANCY RESTRUCTURE (round 4):
// 64-px strip blocks, 4-slot LDS ring = 38,016 B -> 4 blocks/CU
// (16 waves/CU, 4 waves/SIMD; was 2 blocks / 2 waves/SIMD at 75 KB).
// Four independent blocks per CU break the barrier convoy: one block's
// MFMA phase covers another's load latency. Evidence: 3 rounds stuck at
// ~105 us with every pipe <30% regardless of barrier scheme -> pure
// concurrency shortfall.
// Wave tile = 64 px x 16 co (mi=4, ni=1) so regs fit 4 waves/SIMD:
// wreg 9 taps x 2 ks = 18 frags = 72 regs (+acc 16 + staging ~24 < 128,
// enforced by __launch_bounds__(256,4)). Cost: ds_read:MFMA 1:1 (2x LDS
// traffic) -- acceptable, LDS pacing ~= HBM pacing, both overlapped.
// ---------------------------------------------------------------------------
#define BPX 64                      // output px per block
#define PXS 72                      // pixel stride in bf16 elems (64 + 8 pad)
#define ROWPX 66                    // 64 + 2 halo
#define ROW_ELEMS (ROWPX * PXS)     // 4752 shorts = 9,504 B per row

__global__ __launch_bounds__(256, 4) void conv_kernel(
    const float* __restrict__ x, const unsigned short* __restrict__ wbf,
    float* __restrict__ out)
{
    __shared__ unsigned short xs[4 * ROW_ELEMS];   // 38,016 B -> 4 blocks/CU

    const int tid = threadIdx.x;
    const int x0  = blockIdx.x * BPX;
    const int y0  = blockIdx.y * 8;       // multiple of 8 -> slot math uses &3
    const int b   = blockIdx.z;

    // --- staging: 528 items/row (px 0..65 x 8-ch groups of 8 floats) ---
    auto issue = [&](int yin, f32x4* v) {
        const bool rok = (unsigned)yin < (unsigned)HH;
        const float* src = x + ((size_t)(b * HH + (rok ? yin : 0))) * WW * CI;
        #pragma unroll
        for (int k = 0; k < 3; ++k) {
            int i  = tid + k * 256;
            int px = i >> 3, cg = i & 7;
            int xin = x0 - 1 + px;
            bool ok = rok && ((unsigned)xin < (unsigned)WW) && (i < 528);
            const float* p = src + (size_t)xin * CI + cg * 8;
            f32x4 z = {0.f, 0.f, 0.f, 0.f};
            v[2 * k]     = ok ? *(const f32x4*)p       : z;
            v[2 * k + 1] = ok ? *(const f32x4*)(p + 4) : z;
        }
    };
    auto commit = [&](int slot, const f32x4* v) {
        unsigned short* dst = xs + slot * ROW_ELEMS;
        #pragma unroll
        for (int k = 0; k < 3; ++k) {
            int i = tid + k * 256;
            if (k == 2 && i >= 528) continue;
            int px = i >> 3, cg = i & 7;
            u16x8 u;
            #pragma unroll
            for (int e = 0; e < 4; ++e) {
                u[e]     = f2bf(v[2 * k][e]);
                u[e + 4] = f2bf(v[2 * k + 1][e]);
            }
            *(u16x8*)&dst[px * PXS + cg * 8] = u;
        }
    };

    // prologue: input rows y0-1, y0, y0+1 -> slots 0,1,2  (slot = (row+1)&3)
    {
        f32x4 v[6];
        issue(y0 - 1, v); commit(0, v);
        issue(y0,     v); commit(1, v);
        issue(y0 + 1, v); commit(2, v);
    }

    const int wave = tid >> 6, lane = tid & 63;
    const int lm = lane & 15, lq = lane >> 4;
    // wave w owns co quarter [w*16, w*16+16); all waves share px 0..63

    // 18 weight fragments (72 VGPRs), loop-invariant, pinned.
    // wreg[tap][ks]: co = wave*16 + lm, ci = ks*32 + lq*8 .. +7
    u16x8 wreg[9][2];
    {
        const unsigned short* wl = wbf + (size_t)b * 9 * 4096
                                 + (size_t)(wave * 16 + lm) * 64 + lq * 8;
        #pragma unroll
        for (int tap = 0; tap < 9; ++tap)
            #pragma unroll
            for (int ks = 0; ks < 2; ++ks)
                wreg[tap][ks] = *(const u16x8*)(wl + tap * 4096 + ks * 32);
    }
    #pragma unroll
    for (int tap = 0; tap < 9; ++tap)
        #pragma unroll
        for (int ks = 0; ks < 2; ++ks)
            asm volatile("" : "+v"(wreg[tap][ks]));

    __syncthreads();   // prologue barrier (full drain once is fine)

    const int aoff_lane = lm * PXS + lq * 8;

    #pragma unroll
    for (int j = 0; j < 8; ++j) {
        const int y = y0 + j;

        f32x4 acc[4];
        #pragma unroll
        for (int mi = 0; mi < 4; ++mi)
            acc[mi] = (f32x4){0.f, 0.f, 0.f, 0.f};

        const unsigned short* bases[3] = {
            xs + ((y)     & 3) * ROW_ELEMS,
            xs + ((y + 1) & 3) * ROW_ELEMS,
            xs + ((y + 2) & 3) * ROW_ELEMS,
        };

        #pragma unroll
        for (int kh = 0; kh < 3; ++kh) {
            const unsigned short* bs = bases[kh] + aoff_lane;
            #pragma unroll
            for (int kw = 0; kw < 3; ++kw) {
                #pragma unroll
                for (int ks = 0; ks < 2; ++ks) {
                    bf16x8 xf[4];
                    #pragma unroll
                    for (int mi = 0; mi < 4; ++mi)
                        xf[mi] = *(const bf16x8*)(bs + (mi * 16 + kw) * PXS + ks * 32);
                    #pragma unroll
                    for (int mi = 0; mi < 4; ++mi)
                        acc[mi] = __builtin_amdgcn_mfma_f32_16x16x32_bf16(
                            as_bf(wreg[kh * 3 + kw][ks]), xf[mi], acc[mi], 0, 0, 0);
                }
            }
        }

        // stage next input row (y+2) for iter j+1: issue loads first so the
        // epilogue stores (issued after) don't gate the commit's vmcnt wait
        // (vmcnt is FIFO: waiting for the older loads ignores newer stores).
        f32x4 v[6];
        if (j < 7) issue(y + 2, v);

        // epilogue: D col = lane&15 = px-in-tile, row = lq*4+reg = co-in-quarter
        float* op = out + ((size_t)(b * HH + y) * WW + x0) * CO;
        #pragma unroll
        for (int mi = 0; mi < 4; ++mi) {
            int pix = mi * 16 + lm;
            __builtin_nontemporal_store(acc[mi],
                (f32x4*)(op + (size_t)pix * CO + wave * 16 + lq * 4));
        }

        if (j < 7) {
            commit((y + 3) & 3, v);   // input row y+2 -> slot (y+3)&3
            lds_barrier();            // LDS-visibility only; vmem in flight
        }
    }
}

// ---------------------------------------------------------------------------
extern "C" void kernel_launch(void* const* d_in, const int* in_sizes, int n_in,
                              void* d_out, int out_size, void* d_ws, size_t ws_size,
                              hipStream_t stream) {
    const float* inputs     = (const float*)d_in[0];   // [8,256,256,64]
    const float* style      = (const float*)d_in[1];   // [8,512]
    const float* mod_weight = (const float*)d_in[2];   // [512,64]
    const float* mod_bias   = (const float*)d_in[3];   // [64]
    const float* weight     = (const float*)d_in[4];   // [1,64,64,3,3]
    float* out = (float*)d_out;
    unsigned short* wbf = (unsigned short*)d_ws;       // [8][9][64][64] bf16

    modulate_kernel<<<dim3(BATCH, 8), 256, 0, stream>>>(style, mod_weight, mod_bias, weight, wbf);
    conv_kernel<<<dim3(WW / BPX, HH / 8, BATCH), 256, 0, stream>>>(inputs, wbf, out);
}

// Round 5
// 282.339 us; speedup vs baseline: 1.0415x; 1.0415x over previous
//
#include <hip/hip_runtime.h>

#define BATCH 8
#define HH 256
#define WW 256
#define CI 64
#define CO 64
#define STYLE_IN 512

typedef __bf16 bf16x8 __attribute__((ext_vector_type(8)));
typedef float  f32x4  __attribute__((ext_vector_type(4)));
typedef unsigned short u16x8 __attribute__((ext_vector_type(8)));

// round-to-nearest-even fp32 -> bf16
static __device__ inline unsigned short f2bf(float f) {
    union { float f; unsigned int u; } a; a.f = f;
    unsigned int u = a.u;
    u += 0x7fffu + ((u >> 16) & 1u);
    return (unsigned short)(u >> 16);
}

static __device__ inline bf16x8 as_bf(u16x8 v) {
    union { u16x8 u; bf16x8 b; } c; c.u = v; return c.b;
}

// LDS-only barrier: ds ops complete (per-wave lgkmcnt) then s_barrier.
// Does NOT drain vmcnt -> global loads/stores stay in flight (T4).
static __device__ inline void lds_barrier() {
    __builtin_amdgcn_sched_barrier(0);
    asm volatile("s_waitcnt lgkmcnt(0)" ::: "memory");
    __builtin_amdgcn_sched_barrier(0);
    __builtin_amdgcn_s_barrier();
    __builtin_amdgcn_sched_barrier(0);
}

// ---------------------------------------------------------------------------
// Kernel 1: EqualLinear modulation + demodulation -> bf16 weights
// Output layout: wbf[b][tap][co][ci], tap = kh*3+kw, ci contiguous.
// Grid (BATCH, 8); blockIdx.y = co octet.
// ---------------------------------------------------------------------------
__global__ __launch_bounds__(256) void modulate_kernel(
    const float* __restrict__ style, const float* __restrict__ mod_weight,
    const float* __restrict__ mod_bias, const float* __restrict__ weight,
    unsigned short* __restrict__ wbf)
{
    const int b   = blockIdx.x;
    const int oct = blockIdx.y;          // co in [oct*8, oct*8+8)
    const int t   = threadIdx.x;
    __shared__ float sp[4][64];
    __shared__ float s_mod[64];
    __shared__ float dpart[8][32];
    __shared__ float demod[8];

    const float LIN_SCALE  = 0.044194173824159216f;  // 1/sqrt(512)
    const float CONV_SCALE = 0.041666666666666664f;  // 1/sqrt(64*9)

    {
        const int ci = t & 63, part = t >> 6;   // 4 partials per ci
        float acc = 0.f;
        const float* st = style + b * STYLE_IN + part * 128;
        const float* mw = mod_weight + part * 128 * 64 + ci;
        #pragma unroll 8
        for (int j = 0; j < 128; ++j) acc += st[j] * mw[j * 64];
        sp[part][ci] = acc;
    }
    __syncthreads();
    if (t < 64)
        s_mod[t] = (sp[0][t] + sp[1][t] + sp[2][t] + sp[3][t]) * LIN_SCALE + mod_bias[t];
    __syncthreads();

    {
        // demod partials: 8 co x 32 partials, each partial = 2 ci x 9 taps
        const int col = t >> 5, part = t & 31;
        float acc = 0.f;
        const float* wp = weight + (oct * 8 + col) * 576 + part * 18;
        #pragma unroll
        for (int ci2 = 0; ci2 < 2; ++ci2) {
            float s = s_mod[part * 2 + ci2];
            #pragma unroll
            for (int tp = 0; tp < 9; ++tp) {
                float v = wp[ci2 * 9 + tp] * s;
                acc += v * v;
            }
        }
        dpart[col][part] = acc * (CONV_SCALE * CONV_SCALE);
    }
    __syncthreads();
    if (t < 8) {
        float s = 0.f;
        #pragma unroll
        for (int p = 0; p < 32; ++p) s += dpart[t][p];
        demod[t] = rsqrtf(s + 1e-8f);
    }
    __syncthreads();

    // write 8 co x 9 taps x 64 ci = 4608 elems; ci contiguous -> coalesced
    for (int i = t; i < 4608; i += 256) {
        int ci  = i & 63;
        int col = (i >> 6) & 7;
        int tap = i >> 9;
        float v = CONV_SCALE * weight[(oct * 8 + col) * 576 + ci * 9 + tap]
                * s_mod[ci] * demod[col];
        wbf[((b * 9 + tap) * 64 + oct * 8 + col) * 64 + ci] = f2bf(v);
    }
}

// ---------------------------------------------------------------------------
// Kernel 2: implicit-GEMM conv. Round 5 = round-4 occupancy structure
// (64-px strips, 38 KB LDS ring -> 4 blocks/CU, wave = 64px x 16co,
// 18 pinned weight frags) with the two round-4 mistakes fixed:
//  (1) prefetch distance restored to ONE FULL ITERATION: issue(y+3) right
//      after the barrier -> loads in flight across the next MFMA phase
//      (round 4 issued immediately before commit = serial HBM latency
//      at every barrier);
//  (2) plain (cached) output stores instead of nontemporal: each wave
//      writes only 64B per pixel here, the complementary 64B comes from a
//      different wave; nt prevented merge -> WRITE_SIZE 150->187 MB in
//      round 4. Normal stores let L2 combine into full-line writebacks.
// Bank-conflict note: SQ_LDS_BANK_CONFLICT = exactly 4/ds_read_b128 in all
// rounds = benign 2-lanes-per-bank wave64 aliasing; PXS=72 gives each
// 16-lane phase group 2 lanes per 4-dword slot = conflict-free. Not a lever.
// ---------------------------------------------------------------------------
#define BPX 64                      // output px per block
#define PXS 72                      // pixel stride in bf16 elems (64 + 8 pad)
#define ROWPX 66                    // 64 + 2 halo
#define ROW_ELEMS (ROWPX * PXS)     // 4752 shorts = 9,504 B per row

__global__ __launch_bounds__(256, 4) void conv_kernel(
    const float* __restrict__ x, const unsigned short* __restrict__ wbf,
    float* __restrict__ out)
{
    __shared__ unsigned short xs[4 * ROW_ELEMS];   // 38,016 B -> 4 blocks/CU

    const int tid = threadIdx.x;
    const int x0  = blockIdx.x * BPX;
    const int y0  = blockIdx.y * 8;       // multiple of 8 -> slot math uses &3
    const int b   = blockIdx.z;

    // --- staging: 528 items/row (px 0..65 x 8-ch groups of 8 floats) ---
    auto issue = [&](int yin, f32x4* v) {
        const bool rok = (unsigned)yin < (unsigned)HH;
        const float* src = x + ((size_t)(b * HH + (rok ? yin : 0))) * WW * CI;
        #pragma unroll
        for (int k = 0; k < 3; ++k) {
            int i  = tid + k * 256;
            int px = i >> 3, cg = i & 7;
            int xin = x0 - 1 + px;
            bool ok = rok && ((unsigned)xin < (unsigned)WW) && (i < 528);
            const float* p = src + (size_t)xin * CI + cg * 8;
            f32x4 z = {0.f, 0.f, 0.f, 0.f};
            v[2 * k]     = ok ? *(const f32x4*)p       : z;
            v[2 * k + 1] = ok ? *(const f32x4*)(p + 4) : z;
        }
    };
    auto commit = [&](int slot, const f32x4* v) {
        unsigned short* dst = xs + slot * ROW_ELEMS;
        #pragma unroll
        for (int k = 0; k < 3; ++k) {
            int i = tid + k * 256;
            if (k == 2 && i >= 528) continue;
            int px = i >> 3, cg = i & 7;
            u16x8 u;
            #pragma unroll
            for (int e = 0; e < 4; ++e) {
                u[e]     = f2bf(v[2 * k][e]);
                u[e + 4] = f2bf(v[2 * k + 1][e]);
            }
            *(u16x8*)&dst[px * PXS + cg * 8] = u;
        }
    };

    // prologue: input rows y0-1, y0, y0+1 -> slots 0,1,2  (slot = (row+1)&3)
    {
        f32x4 v[6];
        issue(y0 - 1, v); commit(0, v);
        issue(y0,     v); commit(1, v);
        issue(y0 + 1, v); commit(2, v);
    }

    const int wave = tid >> 6, lane = tid & 63;
    const int lm = lane & 15, lq = lane >> 4;
    // wave w owns co quarter [w*16, w*16+16); all waves share px 0..63

    // 18 weight fragments (72 VGPRs), loop-invariant, pinned.
    // wreg[tap][ks]: co = wave*16 + lm, ci = ks*32 + lq*8 .. +7
    u16x8 wreg[9][2];
    {
        const unsigned short* wl = wbf + (size_t)b * 9 * 4096
                                 + (size_t)(wave * 16 + lm) * 64 + lq * 8;
        #pragma unroll
        for (int tap = 0; tap < 9; ++tap)
            #pragma unroll
            for (int ks = 0; ks < 2; ++ks)
                wreg[tap][ks] = *(const u16x8*)(wl + tap * 4096 + ks * 32);
    }
    #pragma unroll
    for (int tap = 0; tap < 9; ++tap)
        #pragma unroll
        for (int ks = 0; ks < 2; ++ks)
            asm volatile("" : "+v"(wreg[tap][ks]));

    __syncthreads();   // prologue barrier (full drain once is fine)

    const int aoff_lane = lm * PXS + lq * 8;

    f32x4 vbuf[6];
    issue(y0 + 2, vbuf);          // row y0+2 in flight over first MFMA phase

    #pragma unroll
    for (int j = 0; j < 8; ++j) {
        const int y = y0 + j;

        f32x4 acc[4];
        #pragma unroll
        for (int mi = 0; mi < 4; ++mi)
            acc[mi] = (f32x4){0.f, 0.f, 0.f, 0.f};

        const unsigned short* bases[3] = {
            xs + ((y)     & 3) * ROW_ELEMS,
            xs + ((y + 1) & 3) * ROW_ELEMS,
            xs + ((y + 2) & 3) * ROW_ELEMS,
        };

        #pragma unroll
        for (int kh = 0; kh < 3; ++kh) {
            const unsigned short* bs = bases[kh] + aoff_lane;
            #pragma unroll
            for (int kw = 0; kw < 3; ++kw) {
                #pragma unroll
                for (int ks = 0; ks < 2; ++ks) {
                    bf16x8 xf[4];
                    #pragma unroll
                    for (int mi = 0; mi < 4; ++mi)
                        xf[mi] = *(const bf16x8*)(bs + (mi * 16 + kw) * PXS + ks * 32);
                    #pragma unroll
                    for (int mi = 0; mi < 4; ++mi)
                        acc[mi] = __builtin_amdgcn_mfma_f32_16x16x32_bf16(
                            as_bf(wreg[kh * 3 + kw][ks]), xf[mi], acc[mi], 0, 0, 0);
                }
            }
        }

        // epilogue: plain cached stores -> L2 merges the 4 waves' 64B
        // half-lines into full 128B-line writebacks.
        // D col = lane&15 = px-in-tile, row = lq*4+reg = co-in-quarter
        float* op = out + ((size_t)(b * HH + y) * WW + x0) * CO;
        #pragma unroll
        for (int mi = 0; mi < 4; ++mi) {
            int pix = mi * 16 + lm;
            *(f32x4*)(op + (size_t)pix * CO + wave * 16 + lq * 4) = acc[mi];
        }

        if (j < 7) {
            // commit row y+2 (in flight since end of iter j-1 / preloop):
            // compiler inserts a counted vmcnt for the vbuf loads; the newer
            // epilogue stores above are NOT drained (vmcnt is FIFO).
            commit((y + 3) & 3, vbuf);
            lds_barrier();            // LDS-visibility only; vmem in flight
            // issue row y+3 now -> in flight across iter j+1's MFMA phase
            issue(y + 3, vbuf);
        }
    }
}

// ---------------------------------------------------------------------------
extern "C" void kernel_launch(void* const* d_in, const int* in_sizes, int n_in,
                              void* d_out, int out_size, void* d_ws, size_t ws_size,
                              hipStream_t stream) {
    const float* inputs     = (const float*)d_in[0];   // [8,256,256,64]
    const float* style      = (const float*)d_in[1];   // [8,512]
    const float* mod_weight = (const float*)d_in[2];   // [512,64]
    const float* mod_bias   = (const float*)d_in[3];   // [64]
    const float* weight     = (const float*)d_in[4];   // [1,64,64,3,3]
    float* out = (float*)d_out;
    unsigned short* wbf = (unsigned short*)d_ws;       // [8][9][64][64] bf16

    modulate_kernel<<<dim3(BATCH, 8), 256, 0, stream>>>(style, mod_weight, mod_bias, weight, wbf);
    conv_kernel<<<dim3(WW / BPX, HH / 8, BATCH), 256, 0, stream>>>(inputs, wbf, out);
}